// Round 1
// baseline (2538.648 us; speedup 1.0000x reference)
//
#include <hip/hip_runtime.h>
#include <stdint.h>

// ---------------- problem constants ----------------
#define CH 512
#define W1 96
#define P1 (W1*W1)        // 9216 descriptor pixels per map
#define W2 192
#define P2 (W2*W2)        // 36864 activation pixels per map
#define TILE 128
#define NT (P1/TILE)      // 72 tiles per dimension
#define BK 16
#define EPSF 1e-8f
#define RDENSE 0.95f
#define RREFINE 0.9f

// ---- packed (value,index): total order, ties -> lower index wins ----
__device__ __forceinline__ unsigned enc_f32(float f){
  unsigned u = __float_as_uint(f);
  return (u & 0x80000000u) ? ~u : (u | 0x80000000u);
}
__device__ __forceinline__ float dec_f32(unsigned e){
  unsigned u = (e & 0x80000000u) ? (e & 0x7FFFFFFFu) : ~e;
  return __uint_as_float(u);
}
__device__ __forceinline__ unsigned long long packVI(float v, int idx){
  return (((unsigned long long)enc_f32(v)) << 32) | (unsigned)(~(unsigned)idx);
}
__device__ __forceinline__ float packedVal(unsigned long long p){ return dec_f32((unsigned)(p >> 32)); }
__device__ __forceinline__ int packedIdx(unsigned long long p){ return (int)(~(unsigned)(p & 0xFFFFFFFFull)); }
__device__ __forceinline__ void merge2(unsigned long long &b, unsigned long long &s, unsigned long long c){
  if (c > b){ s = b; b = c; } else if (c > s){ s = c; }
}

// ---------------- 1. descriptor inverse norms (per pixel over 512 ch) ----------------
__global__ void desc_norm(const float* __restrict__ mA, const float* __restrict__ mB,
                          float* __restrict__ inv1, float* __restrict__ inv2){
  int p = blockIdx.x * blockDim.x + threadIdx.x;   // 0 .. 2*P1
  const float* m = (p < P1) ? mA : mB;
  float* o = (p < P1) ? inv1 : inv2;
  int pix = (p < P1) ? p : p - P1;
  float s = 0.f;
  for (int c = 0; c < CH; ++c){ float v = m[c*P1 + pix]; s += v*v; }
  o[pix] = 1.0f / sqrtf(s);
}

// ---------------- 2. activation inverse norms ----------------
__global__ void act_norm(const float* __restrict__ aA, const float* __restrict__ aB,
                         float* __restrict__ invA, float* __restrict__ invB){
  int p = blockIdx.x * blockDim.x + threadIdx.x;   // 0 .. 2*P2
  const float* m = (p < P2) ? aA : aB;
  float* o = (p < P2) ? invA : invB;
  int pix = (p < P2) ? p : p - P2;
  float s = 0.f;
  for (int c = 0; c < CH; ++c){ float v = m[c*P2 + pix]; s += v*v; }
  o[pix] = 1.0f / sqrtf(s);
}

// ---------------- 3. fused sim-GEMM + per-tile top-2 (rows & cols) ----------------
// C tile 128x128, 256 threads, 8x8 micro-tile, BK=16. fp32 VALU (no fp32 MFMA on CDNA4).
__global__ __launch_bounds__(256)
void sim_tile(const float* __restrict__ mA, const float* __restrict__ mB,
              const float* __restrict__ inv1, const float* __restrict__ inv2,
              unsigned long long* __restrict__ rowCand,
              unsigned long long* __restrict__ colCand){
  __shared__ union {
    struct { float As[BK][TILE]; float Bs[BK][TILE]; } st;     // 16 KB
    unsigned long long colScr[16][TILE][2];                    // 32 KB
  } sm;
  const int rt = blockIdx.y, ct = blockIdx.x;
  const int t = threadIdx.x;
  const int px   = t & 127;        // staging pixel-in-tile
  const int ksub = t >> 7;         // 0..1
  const int rBase = rt * TILE, cBase = ct * TILE;
  const float ivA = inv1[rBase + px];
  const float ivB = inv2[cBase + px];
  const int r0 = (t >> 4) << 3;    // micro-tile row offset
  const int c0 = (t & 15) << 3;    // micro-tile col offset

  float acc[8][8] = {};
  for (int k0 = 0; k0 < CH; k0 += BK){
    #pragma unroll
    for (int u = 0; u < 8; ++u){
      int c = k0 + ksub*8 + u;
      sm.st.As[ksub*8 + u][px] = mA[c*P1 + rBase + px] * ivA;
      sm.st.Bs[ksub*8 + u][px] = mB[c*P1 + cBase + px] * ivB;
    }
    __syncthreads();
    #pragma unroll
    for (int kk = 0; kk < BK; ++kk){
      float4 a0 = *(const float4*)&sm.st.As[kk][r0];
      float4 a1 = *(const float4*)&sm.st.As[kk][r0+4];
      float4 b0 = *(const float4*)&sm.st.Bs[kk][c0];
      float4 b1 = *(const float4*)&sm.st.Bs[kk][c0+4];
      float av[8] = {a0.x,a0.y,a0.z,a0.w,a1.x,a1.y,a1.z,a1.w};
      float bv[8] = {b0.x,b0.y,b0.z,b0.w,b1.x,b1.y,b1.z,b1.w};
      #pragma unroll
      for (int i = 0; i < 8; ++i)
        #pragma unroll
        for (int j = 0; j < 8; ++j)
          acc[i][j] = fmaf(av[i], bv[j], acc[i][j]);
    }
    __syncthreads();
  }

  // ---- row top-2 within tile: per-thread over its 8 cols, then shfl-merge 16 lanes ----
  #pragma unroll
  for (int i = 0; i < 8; ++i){
    unsigned long long b = 0ull, s = 0ull;
    #pragma unroll
    for (int j = 0; j < 8; ++j) merge2(b, s, packVI(acc[i][j], cBase + c0 + j));
    #pragma unroll
    for (int m = 1; m < 16; m <<= 1){
      unsigned long long ob = __shfl_xor(b, m, 64);
      unsigned long long os = __shfl_xor(s, m, 64);
      merge2(b, s, ob); merge2(b, s, os);
    }
    if ((t & 15) == 0){
      int row = rBase + r0 + i;
      rowCand[((long long)ct*P1 + row)*2 + 0] = b;
      rowCand[((long long)ct*P1 + row)*2 + 1] = s;
    }
  }

  // ---- col top-2 within tile: per-thread over its 8 rows -> LDS -> merge over 16 groups ----
  #pragma unroll
  for (int j = 0; j < 8; ++j){
    unsigned long long b = 0ull, s = 0ull;
    #pragma unroll
    for (int i = 0; i < 8; ++i) merge2(b, s, packVI(acc[i][j], rBase + r0 + i));
    sm.colScr[t >> 4][c0 + j][0] = b;
    sm.colScr[t >> 4][c0 + j][1] = s;
  }
  __syncthreads();
  if (t < TILE){
    unsigned long long b = 0ull, s = 0ull;
    #pragma unroll 4
    for (int g = 0; g < 16; ++g){
      merge2(b, s, sm.colScr[g][t][0]);
      merge2(b, s, sm.colScr[g][t][1]);
    }
    colCand[((long long)rt*P1 + cBase + t)*2 + 0] = b;
    colCand[((long long)rt*P1 + cBase + t)*2 + 1] = s;
  }
}

// ---------------- 4. merge per-tile candidates -> global top-2 ----------------
__global__ void merge_cand(const unsigned long long* __restrict__ cand,
                           unsigned long long* __restrict__ top,
                           unsigned long long* __restrict__ sec){
  int p = blockIdx.x * blockDim.x + threadIdx.x;
  unsigned long long b = 0ull, s = 0ull;
  for (int tile = 0; tile < NT; ++tile){
    merge2(b, s, cand[((long long)tile*P1 + p)*2 + 0]);
    merge2(b, s, cand[((long long)tile*P1 + p)*2 + 1]);
  }
  top[p] = b; sec[p] = s;
}

// ---------------- 5. mutual-NN + ratio + border mask ----------------
__global__ void match_k(const unsigned long long* __restrict__ rowTop,
                        const unsigned long long* __restrict__ rowSec,
                        const unsigned long long* __restrict__ colTop,
                        const unsigned long long* __restrict__ colSec,
                        int4* __restrict__ pts, int* __restrict__ validArr){
  int p = blockIdx.x * blockDim.x + threadIdx.x;
  unsigned long long rT = rowTop[p], rS = rowSec[p];
  float s0 = packedVal(rT), s1 = packedVal(rS);
  int nn12 = packedIdx(rT);
  float r12 = (2.f - 2.f*s0) / (2.f - 2.f*s1 + EPSF);
  unsigned long long cT = colTop[nn12], cS = colSec[nn12];
  int nn21 = packedIdx(cT);
  float r21 = (2.f - 2.f*packedVal(cT)) / (2.f - 2.f*packedVal(cS) + EPSF);
  int xA = p % W1, yA = p / W1, xB = nn12 % W1, yB = nn12 / W1;
  bool border = (xA==0)||(xA==W1-1)||(yA==0)||(yA==W1-1)||
                (xB==0)||(xB==W1-1)||(yB==0)||(yB==W1-1);
  bool valid = (nn21 == p) && (r12 <= RDENSE) && (r21 <= RDENSE) && !border;
  pts[p] = valid ? make_int4(xA,yA,xB,yB) : make_int4(0,0,0,0);
  validArr[p] = valid ? 1 : 0;
}

// ---------------- 6. refine: scores[p][4][4] (one wave per point) ----------------
__global__ __launch_bounds__(256)
void refine(const float* __restrict__ actA, const float* __restrict__ actB,
            const float* __restrict__ invA, const float* __restrict__ invB,
            const int4* __restrict__ pts, float* __restrict__ scoresOut){
  int p = (blockIdx.x * blockDim.x + threadIdx.x) >> 6;
  int lane = threadIdx.x & 63;
  int4 q = pts[p];
  const int nbx[4] = {0,0,1,1}, nby[4] = {0,1,0,1};   // NEIGHBORS[:,0], NEIGHBORS[:,1]
  int offA[4], offB[4];
  #pragma unroll
  for (int i = 0; i < 4; ++i){
    offA[i] = (2*q.y + nby[i])*W2 + 2*q.x + nbx[i];
    offB[i] = (2*q.w + nby[i])*W2 + 2*q.z + nbx[i];
  }
  float acc[16] = {};
  #pragma unroll
  for (int k = 0; k < 8; ++k){
    int c = lane + 64*k;
    int base = c * P2;
    float a0 = actA[base+offA[0]], a1 = actA[base+offA[1]],
          a2 = actA[base+offA[2]], a3 = actA[base+offA[3]];
    float b0 = actB[base+offB[0]], b1 = actB[base+offB[1]],
          b2 = actB[base+offB[2]], b3 = actB[base+offB[3]];
    acc[ 0] = fmaf(a0,b0,acc[ 0]); acc[ 1] = fmaf(a0,b1,acc[ 1]);
    acc[ 2] = fmaf(a0,b2,acc[ 2]); acc[ 3] = fmaf(a0,b3,acc[ 3]);
    acc[ 4] = fmaf(a1,b0,acc[ 4]); acc[ 5] = fmaf(a1,b1,acc[ 5]);
    acc[ 6] = fmaf(a1,b2,acc[ 6]); acc[ 7] = fmaf(a1,b3,acc[ 7]);
    acc[ 8] = fmaf(a2,b0,acc[ 8]); acc[ 9] = fmaf(a2,b1,acc[ 9]);
    acc[10] = fmaf(a2,b2,acc[10]); acc[11] = fmaf(a2,b3,acc[11]);
    acc[12] = fmaf(a3,b0,acc[12]); acc[13] = fmaf(a3,b1,acc[13]);
    acc[14] = fmaf(a3,b2,acc[14]); acc[15] = fmaf(a3,b3,acc[15]);
  }
  #pragma unroll
  for (int m = 1; m < 64; m <<= 1)
    #pragma unroll
    for (int u = 0; u < 16; ++u) acc[u] += __shfl_xor(acc[u], m, 64);
  if (lane == 0){
    float sA[4], sB[4];
    #pragma unroll
    for (int i = 0; i < 4; ++i){ sA[i] = invA[offA[i]]; sB[i] = invB[offB[i]]; }
    float4* o = (float4*)(scoresOut + p*16);
    #pragma unroll
    for (int i = 0; i < 4; ++i)
      o[i] = make_float4(acc[i*4+0]*sA[i]*sB[0], acc[i*4+1]*sA[i]*sB[1],
                         acc[i*4+2]*sA[i]*sB[2], acc[i*4+3]*sA[i]*sB[3]);
  }
}

// ---------------- 7. final matching logic + outputs ----------------
__global__ void final_k(const float* __restrict__ scores, const int4* __restrict__ pts,
                        const int* __restrict__ validArr, float* __restrict__ out){
  int p = blockIdx.x * blockDim.x + threadIdx.x;
  float sc[16];
  #pragma unroll
  for (int u = 0; u < 16; ++u) sc[u] = scores[p*16 + u];

  int matchA[4]; float ratioA[4], scoreA[4];
  #pragma unroll
  for (int i = 0; i < 4; ++i){
    int bi = 0; float bv = sc[i*4];
    #pragma unroll
    for (int j = 1; j < 4; ++j) if (sc[i*4+j] > bv){ bv = sc[i*4+j]; bi = j; }
    float sv = -3.402823466e38f;
    #pragma unroll
    for (int j = 0; j < 4; ++j) if (j != bi && sc[i*4+j] > sv){ sv = sc[i*4+j]; }
    matchA[i] = bi;
    float d0 = 2.f - 2.f*bv, d1 = 2.f - 2.f*sv;
    ratioA[i] = d0 / (d1 + EPSF); scoreA[i] = d0;
  }
  int matchB[4]; float ratioB[4];
  #pragma unroll
  for (int j = 0; j < 4; ++j){
    int bi = 0; float bv = sc[j];
    #pragma unroll
    for (int i = 1; i < 4; ++i) if (sc[i*4+j] > bv){ bv = sc[i*4+j]; bi = i; }
    float sv = -3.402823466e38f;
    #pragma unroll
    for (int i = 0; i < 4; ++i) if (i != bi && sc[i*4+j] > sv){ sv = sc[i*4+j]; }
    matchB[j] = bi;
    float d0 = 2.f - 2.f*bv, d1 = 2.f - 2.f*sv;
    ratioB[j] = d0 / (d1 + EPSF);
  }
  bool m[4];
  #pragma unroll
  for (int i = 0; i < 4; ++i)
    m[i] = (fminf(ratioA[i], ratioB[i]) < RREFINE) && (matchB[matchA[i]] == i);
  float smk[4];
  #pragma unroll
  for (int i = 0; i < 4; ++i) smk[i] = m[i] ? scoreA[i] : 5.0f;
  // discard the 2 largest score_masked entries (ties -> lower index, lax.top_k order)
  int d0i = 0; float d0v = smk[0];
  #pragma unroll
  for (int i = 1; i < 4; ++i) if (smk[i] > d0v){ d0v = smk[i]; d0i = i; }
  int d1i = -1; float d1v = -3.402823466e38f;
  #pragma unroll
  for (int i = 0; i < 4; ++i) if (i != d0i && smk[i] > d1v){ d1v = smk[i]; d1i = i; }
  m[d0i] = false; m[d1i] = false;
  bool v = validArr[p] != 0;
  int4 q = pts[p];
  const int nbx[4] = {0,0,1,1}, nby[4] = {0,1,0,1};
  #pragma unroll
  for (int i = 0; i < 4; ++i){
    out[           p*4 + i] = (float)(2*q.x + nbx[i]);            // refined_A x
    out[  P1*4   + p*4 + i] = (float)(2*q.y + nby[i]);            // refined_A y
    out[2*P1*4   + p*4 + i] = (float)(2*q.z + nbx[matchA[i]]);    // refined_B x
    out[3*P1*4   + p*4 + i] = (float)(2*q.w + nby[matchA[i]]);    // refined_B y
    out[4*P1*4   + p*4 + i] = (m[i] && v) ? 1.0f : 0.0f;          // mask
  }
}

// ---------------- launch ----------------
extern "C" void kernel_launch(void* const* d_in, const int* in_sizes, int n_in,
                              void* d_out, int out_size, void* d_ws, size_t ws_size,
                              hipStream_t stream) {
  const float* mapA = (const float*)d_in[0];
  const float* mapB = (const float*)d_in[1];
  const float* actA = (const float*)d_in[2];
  const float* actB = (const float*)d_in[3];
  float* out = (float*)d_out;

  // workspace partition (~22 MB total)
  unsigned long long* rowCand = (unsigned long long*)d_ws;       // NT*P1*2 u64
  unsigned long long* colCand = rowCand + (size_t)NT*P1*2;
  unsigned long long* rowTop  = colCand + (size_t)NT*P1*2;
  unsigned long long* rowSec  = rowTop + P1;
  unsigned long long* colTop  = rowSec + P1;
  unsigned long long* colSec  = colTop + P1;
  float* inv1 = (float*)(colSec + P1);
  float* inv2 = inv1 + P1;
  float* invA = inv2 + P1;
  float* invB = invA + P2;
  int4*  pts  = (int4*)(invB + P2);
  int*   validArr = (int*)(pts + P1);

  float* scoresOut = out + 4*P1*4 + P1*4;   // offset 184320: after refined_A/B + mask

  desc_norm<<<2*P1/256, 256, 0, stream>>>(mapA, mapB, inv1, inv2);
  act_norm <<<2*P2/256, 256, 0, stream>>>(actA, actB, invA, invB);
  sim_tile <<<dim3(NT, NT), 256, 0, stream>>>(mapA, mapB, inv1, inv2, rowCand, colCand);
  merge_cand<<<P1/256, 256, 0, stream>>>(rowCand, rowTop, rowSec);
  merge_cand<<<P1/256, 256, 0, stream>>>(colCand, colTop, colSec);
  match_k  <<<P1/256, 256, 0, stream>>>(rowTop, rowSec, colTop, colSec, pts, validArr);
  refine   <<<P1*64/256, 256, 0, stream>>>(actA, actB, invA, invB, pts, scoresOut);
  final_k  <<<P1/256, 256, 0, stream>>>(scoresOut, pts, validArr, out);
}

// Round 2
// 1669.958 us; speedup vs baseline: 1.5202x; 1.5202x over previous
//
#include <hip/hip_runtime.h>
#include <stdint.h>

// ---------------- problem constants ----------------
#define CH 512
#define W1 96
#define P1 (W1*W1)        // 9216 descriptor pixels per map
#define W2 192
#define P2 (W2*W2)        // 36864 activation pixels per map
#define TILE 128
#define NT (P1/TILE)      // 72 tiles per dimension
#define BK 32             // K-chunk for MFMA GEMM
#define EPSF 1e-8f
#define RDENSE 0.95f
#define RREFINE 0.9f

typedef __attribute__((ext_vector_type(8))) short bf16x8_t;
typedef __attribute__((ext_vector_type(4))) float f32x4_t;

// ---- packed (value,index): total order, ties -> lower index wins ----
__device__ __forceinline__ unsigned enc_f32(float f){
  unsigned u = __float_as_uint(f);
  return (u & 0x80000000u) ? ~u : (u | 0x80000000u);
}
__device__ __forceinline__ float dec_f32(unsigned e){
  unsigned u = (e & 0x80000000u) ? (e & 0x7FFFFFFFu) : ~e;
  return __uint_as_float(u);
}
__device__ __forceinline__ unsigned long long packVI(float v, int idx){
  return (((unsigned long long)enc_f32(v)) << 32) | (unsigned)(~(unsigned)idx);
}
__device__ __forceinline__ float packedVal(unsigned long long p){ return dec_f32((unsigned)(p >> 32)); }
__device__ __forceinline__ int packedIdx(unsigned long long p){ return (int)(~(unsigned)(p & 0xFFFFFFFFull)); }
__device__ __forceinline__ void merge2(unsigned long long &b, unsigned long long &s, unsigned long long c){
  if (c > b){ s = b; b = c; } else if (c > s){ s = c; }
}

// bf16 round-to-nearest-even (bit-exact with HW cvt for normal values)
__device__ __forceinline__ unsigned short f2bf(float f){
  unsigned u = __float_as_uint(f);
  unsigned r = (u + 0x7FFFu + ((u >> 16) & 1u)) >> 16;
  return (unsigned short)r;
}

__device__ __forceinline__ void gload16(const void* g, void* l){
  __builtin_amdgcn_global_load_lds(
      (const __attribute__((address_space(1))) unsigned int*)g,
      (__attribute__((address_space(3))) unsigned int*)l, 16, 0, 0);
}

// ---------------- 1. descriptor inverse norms ----------------
__global__ void desc_norm(const float* __restrict__ mA, const float* __restrict__ mB,
                          float* __restrict__ inv1, float* __restrict__ inv2){
  int p = blockIdx.x * blockDim.x + threadIdx.x;
  const float* m = (p < P1) ? mA : mB;
  float* o = (p < P1) ? inv1 : inv2;
  int pix = (p < P1) ? p : p - P1;
  float s = 0.f;
  for (int c = 0; c < CH; ++c){ float v = m[c*P1 + pix]; s += v*v; }
  o[pix] = 1.0f / sqrtf(s);
}

// ---------------- 2. activation inverse norms ----------------
__global__ void act_norm(const float* __restrict__ aA, const float* __restrict__ aB,
                         float* __restrict__ invA, float* __restrict__ invB){
  int p = blockIdx.x * blockDim.x + threadIdx.x;
  const float* m = (p < P2) ? aA : aB;
  float* o = (p < P2) ? invA : invB;
  int pix = (p < P2) ? p : p - P2;
  float s = 0.f;
  for (int c = 0; c < CH; ++c){ float v = m[c*P2 + pix]; s += v*v; }
  o[pix] = 1.0f / sqrtf(s);
}

// ---------------- 2b. normalize + transpose + split fp32 -> bf16 hi/lo ----------------
// in: src[ch][P1] fp32, out: hi/lo [pix][512] bf16 (row-major per pixel)
__global__ __launch_bounds__(256)
void prep_split(const float* __restrict__ src, const float* __restrict__ inv,
                unsigned short* __restrict__ hi, unsigned short* __restrict__ lo){
  __shared__ float tile[64][65];
  const int pixBase = blockIdx.x * 64;   // 144
  const int chBase  = blockIdx.y * 64;   // 8
  const int t = threadIdx.x;
  #pragma unroll
  for (int rep = 0; rep < 16; ++rep){
    int idx = rep*256 + t;
    int c = idx >> 6, p = idx & 63;
    tile[c][p] = src[(chBase + c)*P1 + pixBase + p];
  }
  __syncthreads();
  const int p = t >> 2, cg = (t & 3) * 16;
  const float iv = inv[pixBase + p];
  unsigned short hbuf[16], lbuf[16];
  #pragma unroll
  for (int j = 0; j < 16; ++j){
    float v = tile[cg + j][p] * iv;
    unsigned short h = f2bf(v);
    float hv = __uint_as_float((unsigned)h << 16);
    unsigned short l2 = f2bf(v - hv);
    hbuf[j] = h; lbuf[j] = l2;
  }
  size_t off = (size_t)(pixBase + p) * CH + chBase + cg;
  *(uint4*)(hi + off)     = ((const uint4*)hbuf)[0];
  *(uint4*)(hi + off + 8) = ((const uint4*)hbuf)[1];
  *(uint4*)(lo + off)     = ((const uint4*)lbuf)[0];
  *(uint4*)(lo + off + 8) = ((const uint4*)lbuf)[1];
}

// ---------------- 3. MFMA sim-GEMM (split bf16: Ah*Bh + Ah*Bl + Al*Bh) + fused top-2 ----
// 128x128 tile, 4 waves (2x2 of 64x64), 16x16x32 MFMA, 4x4 frags/wave, BK=32.
// LDS tiles [128 rows][32 k] bf16, 16B-chunk XOR swizzle: chunk' = chunk ^ ((row>>1)&3),
// baked into the per-lane global source address (linear global_load_lds dest).
__global__ __launch_bounds__(256, 2)
void sim_mfma(const unsigned short* __restrict__ Ah, const unsigned short* __restrict__ Al,
              const unsigned short* __restrict__ Bh, const unsigned short* __restrict__ Bl,
              unsigned long long* __restrict__ rowCand,
              unsigned long long* __restrict__ colCand){
  __shared__ unsigned short ldsT[4][TILE*BK];          // Ah,Al,Bh,Bl : 32 KB
  __shared__ unsigned long long rowScr[TILE][2][2];    // 4 KB
  __shared__ unsigned long long colScr[TILE][2][2];    // 4 KB

  // XCD-aware swizzle (nwg = 5184, % 8 == 0 -> simple form is bijective)
  const int nwg = NT*NT;
  int bid = blockIdx.x;
  int swz = (bid & 7) * (nwg >> 3) + (bid >> 3);
  const int rt = swz / NT, ct = swz % NT;
  const int rBase = rt * TILE, cBase = ct * TILE;

  const int t = threadIdx.x;
  const int w = t >> 6, lane = t & 63;
  const int wr = w >> 1, wc = w & 1;
  const int l15 = lane & 15, lj = lane >> 4;

  // staging: wave w owns tile w. per-lane source pattern for 8 calls/chunk.
  const unsigned short* panel = (w == 0) ? (Ah + (size_t)rBase*CH)
                              : (w == 1) ? (Al + (size_t)rBase*CH)
                              : (w == 2) ? (Bh + (size_t)cBase*CH)
                                         : (Bl + (size_t)cBase*CH);
  int srcOff[8];   // byte offset within panel (k0 added per chunk)
  #pragma unroll
  for (int i = 0; i < 8; ++i){
    int slot = i*64 + lane;
    int row = slot >> 2, chkp = slot & 3;
    int chk = chkp ^ ((row >> 1) & 3);
    srcOff[i] = row * (CH*2) + chk * 16;
  }

  f32x4_t acc[4][4];
  #pragma unroll
  for (int i = 0; i < 4; ++i)
    #pragma unroll
    for (int j = 0; j < 4; ++j)
      #pragma unroll
      for (int r = 0; r < 4; ++r) acc[i][j][r] = 0.f;

  // fragment LDS ushort-offsets (row*32 + swizzled_chunk*8)
  int aOff[4], bOff[4];
  #pragma unroll
  for (int mi = 0; mi < 4; ++mi){
    int rA = wr*64 + mi*16 + l15;
    aOff[mi] = rA*BK + ((lj ^ ((rA >> 1) & 3)) << 3);
  }
  #pragma unroll
  for (int ni = 0; ni < 4; ++ni){
    int rB = wc*64 + ni*16 + l15;
    bOff[ni] = rB*BK + ((lj ^ ((rB >> 1) & 3)) << 3);
  }

  for (int k0 = 0; k0 < CH; k0 += BK){
    const char* pbase = (const char*)panel + k0*2;
    unsigned short* mylds = &ldsT[w][0];
    #pragma unroll
    for (int i = 0; i < 8; ++i)
      gload16(pbase + srcOff[i], mylds + i*512);
    __syncthreads();

    bf16x8_t ah[4], al[4], bh[4], bl[4];
    #pragma unroll
    for (int mi = 0; mi < 4; ++mi){
      ah[mi] = *(const bf16x8_t*)&ldsT[0][aOff[mi]];
      al[mi] = *(const bf16x8_t*)&ldsT[1][aOff[mi]];
    }
    #pragma unroll
    for (int ni = 0; ni < 4; ++ni){
      bh[ni] = *(const bf16x8_t*)&ldsT[2][bOff[ni]];
      bl[ni] = *(const bf16x8_t*)&ldsT[3][bOff[ni]];
    }
    #pragma unroll
    for (int mi = 0; mi < 4; ++mi)
      #pragma unroll
      for (int ni = 0; ni < 4; ++ni){
        acc[mi][ni] = __builtin_amdgcn_mfma_f32_16x16x32_bf16(ah[mi], bh[ni], acc[mi][ni], 0, 0, 0);
        acc[mi][ni] = __builtin_amdgcn_mfma_f32_16x16x32_bf16(ah[mi], bl[ni], acc[mi][ni], 0, 0, 0);
        acc[mi][ni] = __builtin_amdgcn_mfma_f32_16x16x32_bf16(al[mi], bh[ni], acc[mi][ni], 0, 0, 0);
      }
    __syncthreads();
  }

  // ---- fused top-2 epilogue. C/D layout: col = lane&15, row = (lane>>4)*4 + reg ----
  // ROW top-2 (over this wave's 64 cols), then cross-wc merge via LDS
  #pragma unroll
  for (int mi = 0; mi < 4; ++mi){
    #pragma unroll
    for (int reg = 0; reg < 4; ++reg){
      unsigned long long b = 0ull, s = 0ull;
      #pragma unroll
      for (int ni = 0; ni < 4; ++ni){
        int col = cBase + wc*64 + ni*16 + l15;
        merge2(b, s, packVI(acc[mi][ni][reg], col));
      }
      #pragma unroll
      for (int m = 1; m < 16; m <<= 1){
        unsigned long long ob = __shfl_xor(b, m, 64);
        unsigned long long os = __shfl_xor(s, m, 64);
        merge2(b, s, ob); merge2(b, s, os);
      }
      if (l15 == 0){
        int rowLoc = wr*64 + mi*16 + lj*4 + reg;
        rowScr[rowLoc][wc][0] = b; rowScr[rowLoc][wc][1] = s;
      }
    }
  }
  // COL top-2 (over this wave's 64 rows), then cross-wr merge via LDS
  #pragma unroll
  for (int ni = 0; ni < 4; ++ni){
    unsigned long long b = 0ull, s = 0ull;
    #pragma unroll
    for (int mi = 0; mi < 4; ++mi)
      #pragma unroll
      for (int reg = 0; reg < 4; ++reg){
        int row = rBase + wr*64 + mi*16 + lj*4 + reg;
        merge2(b, s, packVI(acc[mi][ni][reg], row));
      }
    #pragma unroll
    for (int m = 16; m < 64; m <<= 1){
      unsigned long long ob = __shfl_xor(b, m, 64);
      unsigned long long os = __shfl_xor(s, m, 64);
      merge2(b, s, ob); merge2(b, s, os);
    }
    if (lj == 0){
      int colLoc = wc*64 + ni*16 + l15;
      colScr[colLoc][wr][0] = b; colScr[colLoc][wr][1] = s;
    }
  }
  __syncthreads();
  if (t < TILE){
    unsigned long long b = 0ull, s = 0ull;
    merge2(b, s, rowScr[t][0][0]); merge2(b, s, rowScr[t][0][1]);
    merge2(b, s, rowScr[t][1][0]); merge2(b, s, rowScr[t][1][1]);
    rowCand[((long long)ct*P1 + rBase + t)*2 + 0] = b;
    rowCand[((long long)ct*P1 + rBase + t)*2 + 1] = s;
  } else {
    int c = t - TILE;
    unsigned long long b = 0ull, s = 0ull;
    merge2(b, s, colScr[c][0][0]); merge2(b, s, colScr[c][0][1]);
    merge2(b, s, colScr[c][1][0]); merge2(b, s, colScr[c][1][1]);
    colCand[((long long)rt*P1 + cBase + c)*2 + 0] = b;
    colCand[((long long)rt*P1 + cBase + c)*2 + 1] = s;
  }
}

// ---------------- 4. merge per-tile candidates -> global top-2 ----------------
__global__ void merge_cand(const unsigned long long* __restrict__ cand,
                           unsigned long long* __restrict__ top,
                           unsigned long long* __restrict__ sec){
  int p = blockIdx.x * blockDim.x + threadIdx.x;
  unsigned long long b = 0ull, s = 0ull;
  for (int tile = 0; tile < NT; ++tile){
    merge2(b, s, cand[((long long)tile*P1 + p)*2 + 0]);
    merge2(b, s, cand[((long long)tile*P1 + p)*2 + 1]);
  }
  top[p] = b; sec[p] = s;
}

// ---------------- 5. mutual-NN + ratio + border mask ----------------
__global__ void match_k(const unsigned long long* __restrict__ rowTop,
                        const unsigned long long* __restrict__ rowSec,
                        const unsigned long long* __restrict__ colTop,
                        const unsigned long long* __restrict__ colSec,
                        int4* __restrict__ pts, int* __restrict__ validArr){
  int p = blockIdx.x * blockDim.x + threadIdx.x;
  unsigned long long rT = rowTop[p], rS = rowSec[p];
  float s0 = packedVal(rT), s1 = packedVal(rS);
  int nn12 = packedIdx(rT);
  float r12 = (2.f - 2.f*s0) / (2.f - 2.f*s1 + EPSF);
  unsigned long long cT = colTop[nn12], cS = colSec[nn12];
  int nn21 = packedIdx(cT);
  float r21 = (2.f - 2.f*packedVal(cT)) / (2.f - 2.f*packedVal(cS) + EPSF);
  int xA = p % W1, yA = p / W1, xB = nn12 % W1, yB = nn12 / W1;
  bool border = (xA==0)||(xA==W1-1)||(yA==0)||(yA==W1-1)||
                (xB==0)||(xB==W1-1)||(yB==0)||(yB==W1-1);
  bool valid = (nn21 == p) && (r12 <= RDENSE) && (r21 <= RDENSE) && !border;
  pts[p] = valid ? make_int4(xA,yA,xB,yB) : make_int4(0,0,0,0);
  validArr[p] = valid ? 1 : 0;
}

// ---------------- 6. refine: scores[p][4][4] (one wave per point) ----------------
__global__ __launch_bounds__(256)
void refine(const float* __restrict__ actA, const float* __restrict__ actB,
            const float* __restrict__ invA, const float* __restrict__ invB,
            const int4* __restrict__ pts, float* __restrict__ scoresOut){
  int p = (blockIdx.x * blockDim.x + threadIdx.x) >> 6;
  int lane = threadIdx.x & 63;
  int4 q = pts[p];
  const int nbx[4] = {0,0,1,1}, nby[4] = {0,1,0,1};
  int offA[4], offB[4];
  #pragma unroll
  for (int i = 0; i < 4; ++i){
    offA[i] = (2*q.y + nby[i])*W2 + 2*q.x + nbx[i];
    offB[i] = (2*q.w + nby[i])*W2 + 2*q.z + nbx[i];
  }
  float acc[16] = {};
  #pragma unroll
  for (int k = 0; k < 8; ++k){
    int c = lane + 64*k;
    int base = c * P2;
    float a0 = actA[base+offA[0]], a1 = actA[base+offA[1]],
          a2 = actA[base+offA[2]], a3 = actA[base+offA[3]];
    float b0 = actB[base+offB[0]], b1 = actB[base+offB[1]],
          b2 = actB[base+offB[2]], b3 = actB[base+offB[3]];
    acc[ 0] = fmaf(a0,b0,acc[ 0]); acc[ 1] = fmaf(a0,b1,acc[ 1]);
    acc[ 2] = fmaf(a0,b2,acc[ 2]); acc[ 3] = fmaf(a0,b3,acc[ 3]);
    acc[ 4] = fmaf(a1,b0,acc[ 4]); acc[ 5] = fmaf(a1,b1,acc[ 5]);
    acc[ 6] = fmaf(a1,b2,acc[ 6]); acc[ 7] = fmaf(a1,b3,acc[ 7]);
    acc[ 8] = fmaf(a2,b0,acc[ 8]); acc[ 9] = fmaf(a2,b1,acc[ 9]);
    acc[10] = fmaf(a2,b2,acc[10]); acc[11] = fmaf(a2,b3,acc[11]);
    acc[12] = fmaf(a3,b0,acc[12]); acc[13] = fmaf(a3,b1,acc[13]);
    acc[14] = fmaf(a3,b2,acc[14]); acc[15] = fmaf(a3,b3,acc[15]);
  }
  #pragma unroll
  for (int m = 1; m < 64; m <<= 1)
    #pragma unroll
    for (int u = 0; u < 16; ++u) acc[u] += __shfl_xor(acc[u], m, 64);
  if (lane == 0){
    float sA[4], sB[4];
    #pragma unroll
    for (int i = 0; i < 4; ++i){ sA[i] = invA[offA[i]]; sB[i] = invB[offB[i]]; }
    float4* o = (float4*)(scoresOut + p*16);
    #pragma unroll
    for (int i = 0; i < 4; ++i)
      o[i] = make_float4(acc[i*4+0]*sA[i]*sB[0], acc[i*4+1]*sA[i]*sB[1],
                         acc[i*4+2]*sA[i]*sB[2], acc[i*4+3]*sA[i]*sB[3]);
  }
}

// ---------------- 7. final matching logic + outputs ----------------
__global__ void final_k(const float* __restrict__ scores, const int4* __restrict__ pts,
                        const int* __restrict__ validArr, float* __restrict__ out){
  int p = blockIdx.x * blockDim.x + threadIdx.x;
  float sc[16];
  #pragma unroll
  for (int u = 0; u < 16; ++u) sc[u] = scores[p*16 + u];

  int matchA[4]; float ratioA[4], scoreA[4];
  #pragma unroll
  for (int i = 0; i < 4; ++i){
    int bi = 0; float bv = sc[i*4];
    #pragma unroll
    for (int j = 1; j < 4; ++j) if (sc[i*4+j] > bv){ bv = sc[i*4+j]; bi = j; }
    float sv = -3.402823466e38f;
    #pragma unroll
    for (int j = 0; j < 4; ++j) if (j != bi && sc[i*4+j] > sv){ sv = sc[i*4+j]; }
    matchA[i] = bi;
    float d0 = 2.f - 2.f*bv, d1 = 2.f - 2.f*sv;
    ratioA[i] = d0 / (d1 + EPSF); scoreA[i] = d0;
  }
  int matchB[4]; float ratioB[4];
  #pragma unroll
  for (int j = 0; j < 4; ++j){
    int bi = 0; float bv = sc[j];
    #pragma unroll
    for (int i = 1; i < 4; ++i) if (sc[i*4+j] > bv){ bv = sc[i*4+j]; bi = i; }
    float sv = -3.402823466e38f;
    #pragma unroll
    for (int i = 0; i < 4; ++i) if (i != bi && sc[i*4+j] > sv){ sv = sc[i*4+j]; }
    matchB[j] = bi;
    float d0 = 2.f - 2.f*bv, d1 = 2.f - 2.f*sv;
    ratioB[j] = d0 / (d1 + EPSF);
  }
  bool m[4];
  #pragma unroll
  for (int i = 0; i < 4; ++i)
    m[i] = (fminf(ratioA[i], ratioB[i]) < RREFINE) && (matchB[matchA[i]] == i);
  float smk[4];
  #pragma unroll
  for (int i = 0; i < 4; ++i) smk[i] = m[i] ? scoreA[i] : 5.0f;
  int d0i = 0; float d0v = smk[0];
  #pragma unroll
  for (int i = 1; i < 4; ++i) if (smk[i] > d0v){ d0v = smk[i]; d0i = i; }
  int d1i = -1; float d1v = -3.402823466e38f;
  #pragma unroll
  for (int i = 0; i < 4; ++i) if (i != d0i && smk[i] > d1v){ d1v = smk[i]; d1i = i; }
  m[d0i] = false; m[d1i] = false;
  bool v = validArr[p] != 0;
  int4 q = pts[p];
  const int nbx[4] = {0,0,1,1}, nby[4] = {0,1,0,1};
  #pragma unroll
  for (int i = 0; i < 4; ++i){
    out[           p*4 + i] = (float)(2*q.x + nbx[i]);
    out[  P1*4   + p*4 + i] = (float)(2*q.y + nby[i]);
    out[2*P1*4   + p*4 + i] = (float)(2*q.z + nbx[matchA[i]]);
    out[3*P1*4   + p*4 + i] = (float)(2*q.w + nby[matchA[i]]);
    out[4*P1*4   + p*4 + i] = (m[i] && v) ? 1.0f : 0.0f;
  }
}

// ---------------- launch ----------------
extern "C" void kernel_launch(void* const* d_in, const int* in_sizes, int n_in,
                              void* d_out, int out_size, void* d_ws, size_t ws_size,
                              hipStream_t stream) {
  const float* mapA = (const float*)d_in[0];
  const float* mapB = (const float*)d_in[1];
  const float* actA = (const float*)d_in[2];
  const float* actB = (const float*)d_in[3];
  float* out = (float*)d_out;

  // workspace partition (~60 MB total)
  unsigned short* Ah = (unsigned short*)d_ws;                 // [P1][512] bf16
  unsigned short* Al = Ah + (size_t)P1*CH;
  unsigned short* Bh = Al + (size_t)P1*CH;
  unsigned short* Bl = Bh + (size_t)P1*CH;
  unsigned long long* rowCand = (unsigned long long*)(Bl + (size_t)P1*CH);  // NT*P1*2
  unsigned long long* colCand = rowCand + (size_t)NT*P1*2;
  unsigned long long* rowTop  = colCand + (size_t)NT*P1*2;
  unsigned long long* rowSec  = rowTop + P1;
  unsigned long long* colTop  = rowSec + P1;
  unsigned long long* colSec  = colTop + P1;
  float* inv1 = (float*)(colSec + P1);
  float* inv2 = inv1 + P1;
  float* invA = inv2 + P1;
  float* invB = invA + P2;
  int4*  pts  = (int4*)(invB + P2);
  int*   validArr = (int*)(pts + P1);

  float* scoresOut = out + 4*P1*4 + P1*4;   // after refined_A/B + mask

  desc_norm <<<2*P1/256, 256, 0, stream>>>(mapA, mapB, inv1, inv2);
  act_norm  <<<2*P2/256, 256, 0, stream>>>(actA, actB, invA, invB);
  prep_split<<<dim3(P1/64, CH/64), 256, 0, stream>>>(mapA, inv1, Ah, Al);
  prep_split<<<dim3(P1/64, CH/64), 256, 0, stream>>>(mapB, inv2, Bh, Bl);
  sim_mfma  <<<NT*NT, 256, 0, stream>>>(Ah, Al, Bh, Bl, rowCand, colCand);
  merge_cand<<<P1/256, 256, 0, stream>>>(rowCand, rowTop, rowSec);
  merge_cand<<<P1/256, 256, 0, stream>>>(colCand, colTop, colSec);
  match_k   <<<P1/256, 256, 0, stream>>>(rowTop, rowSec, colTop, colSec, pts, validArr);
  refine    <<<P1*64/256, 256, 0, stream>>>(actA, actB, invA, invB, pts, scoresOut);
  final_k   <<<P1/256, 256, 0, stream>>>(scoresOut, pts, validArr, out);
}